// Round 1
// baseline (537.556 us; speedup 1.0000x reference)
//
#include <hip/hip_runtime.h>

#define M_TOK 8192
#define N_OUT 4096
#define K_DIM 4096
#define NGROUPS 32          // K/128
#define K_TILES 128         // K/32

typedef __bf16 bf16x8 __attribute__((ext_vector_type(8)));
typedef __bf16 bf16x4 __attribute__((ext_vector_type(4)));
typedef float  f32x4  __attribute__((ext_vector_type(4)));

#define GLOBAL_CVP const __attribute__((address_space(1))) void*
#define LDS_VP __attribute__((address_space(3))) void*

// ---------------- prep: x fp32 -> bf16 ----------------
__global__ __launch_bounds__(256)
void convert_x_kernel(const float* __restrict__ x, __bf16* __restrict__ xb) {
    const size_t total = (size_t)M_TOK * K_DIM / 8;   // bf16x8 chunks
    for (size_t i = (size_t)blockIdx.x * blockDim.x + threadIdx.x; i < total;
         i += (size_t)gridDim.x * blockDim.x) {
        const float4 v0 = ((const float4*)x)[2 * i];
        const float4 v1 = ((const float4*)x)[2 * i + 1];
        bf16x8 b;
        b[0] = (__bf16)v0.x; b[1] = (__bf16)v0.y; b[2] = (__bf16)v0.z; b[3] = (__bf16)v0.w;
        b[4] = (__bf16)v1.x; b[5] = (__bf16)v1.y; b[6] = (__bf16)v1.z; b[7] = (__bf16)v1.w;
        ((bf16x8*)xb)[i] = b;
    }
}

// ---------------- prep: dequant wq int32 -> bf16 ----------------
__global__ __launch_bounds__(256)
void dequant_w_kernel(const int* __restrict__ wq, const float* __restrict__ scales,
                      const float* __restrict__ zeros, __bf16* __restrict__ wb) {
    const size_t total = (size_t)N_OUT * K_DIM / 8;
    for (size_t i = (size_t)blockIdx.x * blockDim.x + threadIdx.x; i < total;
         i += (size_t)gridDim.x * blockDim.x) {
        const int4 q0 = ((const int4*)wq)[2 * i];
        const int4 q1 = ((const int4*)wq)[2 * i + 1];
        const size_t e = i * 8;
        const int row = (int)(e >> 12);      // / 4096
        const int g   = ((int)e & 4095) >> 7; // group within row (8 | 128, no straddle)
        const float s = scales[row * NGROUPS + g];
        const float z = zeros [row * NGROUPS + g];
        bf16x8 b;
        b[0] = (__bf16)fmaf((float)q0.x, s, z);
        b[1] = (__bf16)fmaf((float)q0.y, s, z);
        b[2] = (__bf16)fmaf((float)q0.z, s, z);
        b[3] = (__bf16)fmaf((float)q0.w, s, z);
        b[4] = (__bf16)fmaf((float)q1.x, s, z);
        b[5] = (__bf16)fmaf((float)q1.y, s, z);
        b[6] = (__bf16)fmaf((float)q1.z, s, z);
        b[7] = (__bf16)fmaf((float)q1.w, s, z);
        ((bf16x8*)wb)[i] = b;
    }
}

// ---------------- main: bf16 GEMM, B^T input, 256^2 tile, 4-slot ring ----
// A [M,K] row-major bf16, B [N,K] row-major bf16, out[M,N] fp32 = A.B^T + bias
//
// Structure (T1/T3/T4/T5 from the catalog):
//  - BM=BN=256, BK=32, 512 threads = 8 waves (2M x 4N), per-wave C = 128x64
//  - LDS: 4-slot ring per matrix (4 x 256x32 bf16 = 64 KB each, 128 KB total)
//    -> prefetch distance 3 K-tiles, vmcnt(8) steady state (never 0 in loop)
//  - one raw s_barrier per K-tile (no __syncthreads drain)
//  - BK=32 => 64-B LDS row stride => fragment ds_read_b128 is naturally
//    bank-even (8 lanes/bank, the b128 minimum) -> no swizzle needed
//  - setprio(1) around the 32-MFMA cluster
//  - bijective XCD swizzle: 512 wgs = 8 XCDs x 64; each XCD owns 2 B-panels
//
// Race argument (slot = t&3):
//  - STAGE(t+3) writes slot (t-1)&3, whose last reads (tile t-1) completed
//    before the phase-(t-1) barrier every wave crossed before issuing STAGE.
//  - KBODY(t) reads tile t, whose loads were issued at phase t-3; vmcnt(8)
//    at phase t-1 leaves only tiles t+1,t+2 in flight, so tile t has landed,
//    and the barrier after it makes the LDS writes visible to all waves.
__global__ __launch_bounds__(512, 2)
void gemm_bt256_kernel(const __bf16* __restrict__ A, const __bf16* __restrict__ B,
                       const float* __restrict__ bias, float* __restrict__ out) {
    __shared__ __bf16 As[4 * 8192];   // 64 KB: 4 slots of [256 rows][32 cols]
    __shared__ __bf16 Bs[4 * 8192];   // 64 KB

    const int tid  = threadIdx.x;
    const int wid  = tid >> 6;
    const int lane = tid & 63;

    // XCD-aware bijective swizzle (512 = 8 * 64, exact)
    const int s   = blockIdx.x;
    const int swz = (s & 7) * 64 + (s >> 3);
    const int m0  = (swz & 31) * 256;   // 32 M-blocks
    const int n0  = (swz >> 5) * 256;   // 16 N-blocks; per XCD: nb in {2 vals}

    const int lrow  = lane & 15;
    const int quad  = lane >> 4;
    const int wmRow = (wid >> 2) * 128;  // wave's A-row base within tile
    const int wnRow = (wid & 3) * 64;    // wave's B-row base within tile

    // staging geometry: wave w covers 16 rows per 128-row half; lane covers
    // row (lane>>2), 16 B at col-byte (lane&3)*16. LDS dest is wave-uniform
    // base + lane*16 (global_load_lds rule) -> linear row-major layout.
    const __bf16* Abase = A + (size_t)(m0 + wid * 16 + (lane >> 2)) * K_DIM + (lane & 3) * 8;
    const __bf16* Bbase = B + (size_t)(n0 + wid * 16 + (lane >> 2)) * K_DIM + (lane & 3) * 8;

    f32x4 acc[8][4];
#pragma unroll
    for (int i = 0; i < 8; ++i)
#pragma unroll
        for (int j = 0; j < 4; ++j)
            acc[i][j] = (f32x4){0.f, 0.f, 0.f, 0.f};

#define STAGE(T)                                                                            \
    {                                                                                       \
        const int    _s  = (T) & 3;                                                         \
        const size_t _k  = (size_t)(T) * 32;                                                \
        const __bf16* _ga = Abase + _k;                                                     \
        const __bf16* _gb = Bbase + _k;                                                     \
        __bf16* _la = (__bf16*)As + _s * 8192 + wid * 512;                                  \
        __bf16* _lb = (__bf16*)Bs + _s * 8192 + wid * 512;                                  \
        __builtin_amdgcn_global_load_lds((GLOBAL_CVP)(_ga), (LDS_VP)(_la), 16, 0, 0);       \
        __builtin_amdgcn_global_load_lds((GLOBAL_CVP)(_ga + (size_t)128 * K_DIM),           \
                                         (LDS_VP)(_la + 4096), 16, 0, 0);                   \
        __builtin_amdgcn_global_load_lds((GLOBAL_CVP)(_gb), (LDS_VP)(_lb), 16, 0, 0);       \
        __builtin_amdgcn_global_load_lds((GLOBAL_CVP)(_gb + (size_t)128 * K_DIM),           \
                                         (LDS_VP)(_lb + 4096), 16, 0, 0);                   \
    }

#define KBODY(T)                                                                            \
    {                                                                                       \
        const int _s = (T) & 3;                                                             \
        const __bf16* _As = (const __bf16*)As + _s * 8192;                                  \
        const __bf16* _Bs = (const __bf16*)Bs + _s * 8192;                                  \
        bf16x8 _af[8], _bf[4];                                                              \
        _Pragma("unroll")                                                                   \
        for (int _i = 0; _i < 8; ++_i)                                                      \
            _af[_i] = *(const bf16x8*)&_As[(wmRow + _i * 16 + lrow) * 32 + quad * 8];       \
        _Pragma("unroll")                                                                   \
        for (int _j = 0; _j < 4; ++_j)                                                      \
            _bf[_j] = *(const bf16x8*)&_Bs[(wnRow + _j * 16 + lrow) * 32 + quad * 8];       \
        __builtin_amdgcn_s_setprio(1);                                                      \
        _Pragma("unroll")                                                                   \
        for (int _i = 0; _i < 8; ++_i)                                                      \
            _Pragma("unroll")                                                               \
            for (int _j = 0; _j < 4; ++_j)                                                  \
                acc[_i][_j] = __builtin_amdgcn_mfma_f32_16x16x32_bf16(_af[_i], _bf[_j],     \
                                                                      acc[_i][_j], 0, 0, 0);\
        __builtin_amdgcn_s_setprio(0);                                                      \
    }

#define SYNC(VM)                                                                            \
    {                                                                                       \
        __builtin_amdgcn_sched_barrier(0);                                                  \
        asm volatile("s_waitcnt vmcnt(" #VM ")" ::: "memory");                              \
        __builtin_amdgcn_s_barrier();                                                       \
        __builtin_amdgcn_sched_barrier(0);                                                  \
    }

    // prologue: fill 3 ring slots, wait for tile 0 (leave 1,2 in flight)
    STAGE(0); STAGE(1); STAGE(2);
    SYNC(8);

    // main loop: stage t+3, compute t, wait so tile t+1 has landed
#pragma unroll 4
    for (int t = 0; t < K_TILES - 3; ++t) {
        STAGE(t + 3);
        KBODY(t);
        SYNC(8);
    }
    // epilogue peel: drain the ring (only place vmcnt goes below 8)
    KBODY(K_TILES - 3); SYNC(4);
    KBODY(K_TILES - 2); SYNC(0);
    KBODY(K_TILES - 1);

#undef STAGE
#undef KBODY
#undef SYNC

    // epilogue: D row=(lane>>4)*4+reg, col=lane&15 (m89-verified) ; add bias
#pragma unroll
    for (int j = 0; j < 4; ++j) {
        const int col = n0 + wnRow + j * 16 + lrow;
        const float bv = bias[col];
#pragma unroll
        for (int i = 0; i < 8; ++i) {
            const int rowb = m0 + wmRow + i * 16 + quad * 4;
#pragma unroll
            for (int r = 0; r < 4; ++r)
                out[(size_t)(rowb + r) * N_OUT + col] = acc[i][j][r] + bv;
        }
    }
}

// ---------------- fallback (round-1 fused kernel, used if ws too small) ----
#define LDS_STRIDE 40
__global__ __launch_bounds__(256)
void qlinear_fused_kernel(const float* __restrict__ x,
                          const int*   __restrict__ wq,
                          const float* __restrict__ scales,
                          const float* __restrict__ zeros,
                          const float* __restrict__ bias,
                          float*       __restrict__ out)
{
    __shared__ __bf16 As[128 * LDS_STRIDE];
    __shared__ __bf16 Bs[128 * LDS_STRIDE];
    const int tid  = threadIdx.x;
    const int m0   = blockIdx.x * 128;
    const int n0   = blockIdx.y * 128;
    const int wave = tid >> 6;
    const int lane = tid & 63;
    const int wm   = (wave & 1) * 64;
    const int wn   = (wave >> 1) * 64;
    const int lrow = lane & 15;
    const int quad = lane >> 4;
    const int srow = tid >> 3;
    const int scol = (tid & 7) * 4;

    f32x4 acc[4][4];
#pragma unroll
    for (int i = 0; i < 4; i++)
#pragma unroll
        for (int j = 0; j < 4; j++)
            acc[i][j] = (f32x4){0.f, 0.f, 0.f, 0.f};

    for (int k0 = 0; k0 < K_DIM; k0 += 32) {
        const int g = k0 >> 7;
#pragma unroll
        for (int rr = 0; rr < 4; rr++) {
            const int row = srow + rr * 32;
            const float4 v = *(const float4*)(x + (size_t)(m0 + row) * K_DIM + k0 + scol);
            bf16x4 b;
            b[0] = (__bf16)v.x; b[1] = (__bf16)v.y;
            b[2] = (__bf16)v.z; b[3] = (__bf16)v.w;
            *(bf16x4*)&As[row * LDS_STRIDE + scol] = b;
        }
#pragma unroll
        for (int rr = 0; rr < 4; rr++) {
            const int row = srow + rr * 32;
            const int4 q = *(const int4*)(wq + (size_t)(n0 + row) * K_DIM + k0 + scol);
            const float s = scales[(n0 + row) * NGROUPS + g];
            const float z = zeros [(n0 + row) * NGROUPS + g];
            bf16x4 b;
            b[0] = (__bf16)fmaf((float)q.x, s, z);
            b[1] = (__bf16)fmaf((float)q.y, s, z);
            b[2] = (__bf16)fmaf((float)q.z, s, z);
            b[3] = (__bf16)fmaf((float)q.w, s, z);
            *(bf16x4*)&Bs[row * LDS_STRIDE + scol] = b;
        }
        __syncthreads();
        bf16x8 af[4], bfr[4];
#pragma unroll
        for (int i = 0; i < 4; i++) {
            af[i]  = *(const bf16x8*)&As[(wm + i * 16 + lrow) * LDS_STRIDE + quad * 8];
            bfr[i] = *(const bf16x8*)&Bs[(wn + i * 16 + lrow) * LDS_STRIDE + quad * 8];
        }
#pragma unroll
        for (int i = 0; i < 4; i++)
#pragma unroll
            for (int j = 0; j < 4; j++)
                acc[i][j] = __builtin_amdgcn_mfma_f32_16x16x32_bf16(af[i], bfr[j], acc[i][j], 0, 0, 0);
        __syncthreads();
    }
#pragma unroll
    for (int j = 0; j < 4; j++) {
        const int col = n0 + wn + j * 16 + lrow;
        const float bv = bias[col];
#pragma unroll
        for (int i = 0; i < 4; i++) {
            const int rowb = m0 + wm + i * 16 + quad * 4;
#pragma unroll
            for (int r = 0; r < 4; r++)
                out[(size_t)(rowb + r) * N_OUT + col] = acc[i][j][r] + bv;
        }
    }
}

extern "C" void kernel_launch(void* const* d_in, const int* in_sizes, int n_in,
                              void* d_out, int out_size, void* d_ws, size_t ws_size,
                              hipStream_t stream) {
    const float* x      = (const float*)d_in[0];
    const int*   wq     = (const int*)  d_in[1];
    const float* scales = (const float*)d_in[2];
    const float* zeros  = (const float*)d_in[3];
    const float* bias   = (const float*)d_in[4];
    float*       out    = (float*)d_out;

    const size_t xb_bytes = (size_t)M_TOK * K_DIM * 2;   // 67.1 MB
    const size_t wb_bytes = (size_t)N_OUT * K_DIM * 2;   // 33.6 MB

    if (ws_size >= xb_bytes + wb_bytes) {
        __bf16* xb = (__bf16*)d_ws;
        __bf16* wb = (__bf16*)((char*)d_ws + xb_bytes);
        convert_x_kernel<<<4096, 256, 0, stream>>>(x, xb);
        dequant_w_kernel<<<2048, 256, 0, stream>>>(wq, scales, zeros, wb);
        dim3 grid((M_TOK / 256) * (N_OUT / 256));   // 512 wgs, 1D for XCD swizzle
        gemm_bt256_kernel<<<grid, 512, 0, stream>>>(xb, wb, bias, out);
    } else {
        dim3 grid(M_TOK / 128, N_OUT / 128);
        qlinear_fused_kernel<<<grid, 256, 0, stream>>>(x, wq, scales, zeros, bias, out);
    }
}

// Round 4
// 529.793 us; speedup vs baseline: 1.0147x; 1.0147x over previous
//
#include <hip/hip_runtime.h>

#define M_TOK 8192
#define N_OUT 4096
#define K_DIM 4096
#define NGROUPS 32          // K/128
#define K_TILES 128         // K/32

typedef __bf16 bf16x8 __attribute__((ext_vector_type(8)));
typedef __bf16 bf16x4 __attribute__((ext_vector_type(4)));
typedef float  f32x4  __attribute__((ext_vector_type(4)));

#define GLOBAL_CVP const __attribute__((address_space(1))) void*
#define LDS_VP __attribute__((address_space(3))) void*

// ---------------- prep: fused x-convert + w-dequant (concurrent) ----------
#define XBLOCKS 2048
#define WBLOCKS 1024
__global__ __launch_bounds__(256)
void prep_kernel(const float* __restrict__ x, __bf16* __restrict__ xb,
                 const int* __restrict__ wq, const float* __restrict__ scales,
                 const float* __restrict__ zeros, __bf16* __restrict__ wb) {
    if (blockIdx.x < XBLOCKS) {
        const size_t total = (size_t)M_TOK * K_DIM / 8;   // bf16x8 chunks
        for (size_t i = (size_t)blockIdx.x * blockDim.x + threadIdx.x; i < total;
             i += (size_t)XBLOCKS * blockDim.x) {
            const float4 v0 = ((const float4*)x)[2 * i];
            const float4 v1 = ((const float4*)x)[2 * i + 1];
            bf16x8 b;
            b[0] = (__bf16)v0.x; b[1] = (__bf16)v0.y; b[2] = (__bf16)v0.z; b[3] = (__bf16)v0.w;
            b[4] = (__bf16)v1.x; b[5] = (__bf16)v1.y; b[6] = (__bf16)v1.z; b[7] = (__bf16)v1.w;
            ((bf16x8*)xb)[i] = b;
        }
    } else {
        const size_t total = (size_t)N_OUT * K_DIM / 8;
        for (size_t i = (size_t)(blockIdx.x - XBLOCKS) * blockDim.x + threadIdx.x; i < total;
             i += (size_t)WBLOCKS * blockDim.x) {
            const int4 q0 = ((const int4*)wq)[2 * i];
            const int4 q1 = ((const int4*)wq)[2 * i + 1];
            const size_t e = i * 8;
            const int row = (int)(e >> 12);       // / 4096
            const int g   = ((int)e & 4095) >> 7; // group within row (8 | 128, no straddle)
            const float s = scales[row * NGROUPS + g];
            const float z = zeros [row * NGROUPS + g];
            bf16x8 b;
            b[0] = (__bf16)fmaf((float)q0.x, s, z);
            b[1] = (__bf16)fmaf((float)q0.y, s, z);
            b[2] = (__bf16)fmaf((float)q0.z, s, z);
            b[3] = (__bf16)fmaf((float)q0.w, s, z);
            b[4] = (__bf16)fmaf((float)q1.x, s, z);
            b[5] = (__bf16)fmaf((float)q1.y, s, z);
            b[6] = (__bf16)fmaf((float)q1.z, s, z);
            b[7] = (__bf16)fmaf((float)q1.w, s, z);
            ((bf16x8*)wb)[i] = b;
        }
    }
}

// ---------------- main: bf16 GEMM, B^T input, 256^2 tile, 4-slot ring ----
// A [M,K] row-major bf16, B [N,K] row-major bf16, out[M,N] fp32 = A.B^T + bias
//
//  - BM=BN=256, BK=32, 512 threads = 8 waves (2M x 4N), per-wave C = 128x64
//  - LDS: 4-slot ring per matrix (128 KB total), prefetch distance 3,
//    vmcnt(8) steady state (T4: never 0 in main loop)
//  - one raw s_barrier per K-tile
//  - T2 swizzle for BK=32 (64-B rows): physical 16B slot of (row, slot q)
//    is q ^ ((row>>1)&3).  Rule 21: global_load_lds writes LINEARLY, so the
//    inverse permutation is applied to the per-lane GLOBAL source address
//    (scol = (lane&3) ^ ((lane>>3)&3); note lane>>3 == (row>>1) since
//    row = lane>>2), and the same involution on the ds_read side.
//    Per 8-lane service group the 16B-granule indices become
//    {0,4,1,5,2,6,3,7} -> conflict-free.
//  - setprio(1) around the 32-MFMA cluster (T5)
//  - bijective XCD swizzle: 512 wgs = 8 XCDs x 64 (T1)
__global__ __launch_bounds__(512, 2)
void gemm_bt256_kernel(const __bf16* __restrict__ A, const __bf16* __restrict__ B,
                       const float* __restrict__ bias, float* __restrict__ out) {
    __shared__ __bf16 As[4 * 8192];   // 64 KB: 4 slots of [256 rows][32 cols]
    __shared__ __bf16 Bs[4 * 8192];   // 64 KB

    const int tid  = threadIdx.x;
    const int wid  = tid >> 6;
    const int lane = tid & 63;

    // XCD-aware bijective swizzle (512 = 8 * 64, exact)
    const int s   = blockIdx.x;
    const int swz = (s & 7) * 64 + (s >> 3);
    const int m0  = (swz & 31) * 256;   // 32 M-blocks
    const int n0  = (swz >> 5) * 256;   // 16 N-blocks

    const int lrow  = lane & 15;
    const int quad  = lane >> 4;
    const int wmRow = (wid >> 2) * 128;  // wave's A-row base within tile
    const int wnRow = (wid & 3) * 64;    // wave's B-row base within tile
    // swizzled 16B-slot byte offset for fragment reads (involution of stage swz)
    const int sq = (quad ^ ((lrow >> 1) & 3)) * 8;

    // staging: lane l covers row (l>>2); global col-slot is pre-swizzled so
    // that the LINEAR LDS write lands data where the swizzled read expects it
    const int scol = ((lane & 3) ^ ((lane >> 3) & 3)) * 8;
    const __bf16* Abase = A + (size_t)(m0 + wid * 16 + (lane >> 2)) * K_DIM + scol;
    const __bf16* Bbase = B + (size_t)(n0 + wid * 16 + (lane >> 2)) * K_DIM + scol;

    f32x4 acc[8][4];
#pragma unroll
    for (int i = 0; i < 8; ++i)
#pragma unroll
        for (int j = 0; j < 4; ++j)
            acc[i][j] = (f32x4){0.f, 0.f, 0.f, 0.f};

#define STAGE(T)                                                                            \
    {                                                                                       \
        const int    _s  = (T) & 3;                                                         \
        const size_t _k  = (size_t)(T) * 32;                                                \
        const __bf16* _ga = Abase + _k;                                                     \
        const __bf16* _gb = Bbase + _k;                                                     \
        __bf16* _la = (__bf16*)As + _s * 8192 + wid * 512;                                  \
        __bf16* _lb = (__bf16*)Bs + _s * 8192 + wid * 512;                                  \
        __builtin_amdgcn_global_load_lds((GLOBAL_CVP)(_ga), (LDS_VP)(_la), 16, 0, 0);       \
        __builtin_amdgcn_global_load_lds((GLOBAL_CVP)(_ga + (size_t)128 * K_DIM),           \
                                         (LDS_VP)(_la + 4096), 16, 0, 0);                   \
        __builtin_amdgcn_global_load_lds((GLOBAL_CVP)(_gb), (LDS_VP)(_lb), 16, 0, 0);       \
        __builtin_amdgcn_global_load_lds((GLOBAL_CVP)(_gb + (size_t)128 * K_DIM),           \
                                         (LDS_VP)(_lb + 4096), 16, 0, 0);                   \
    }

#define KBODY(T)                                                                            \
    {                                                                                       \
        const int _s = (T) & 3;                                                             \
        const __bf16* _As = (const __bf16*)As + _s * 8192;                                  \
        const __bf16* _Bs = (const __bf16*)Bs + _s * 8192;                                  \
        bf16x8 _af[8], _bf[4];                                                              \
        _Pragma("unroll")                                                                   \
        for (int _j = 0; _j < 4; ++_j)                                                      \
            _bf[_j] = *(const bf16x8*)&_Bs[(wnRow + _j * 16 + lrow) * 32 + sq];             \
        _Pragma("unroll")                                                                   \
        for (int _i = 0; _i < 8; ++_i)                                                      \
            _af[_i] = *(const bf16x8*)&_As[(wmRow + _i * 16 + lrow) * 32 + sq];             \
        __builtin_amdgcn_s_setprio(1);                                                      \
        _Pragma("unroll")                                                                   \
        for (int _i = 0; _i < 8; ++_i)                                                      \
            _Pragma("unroll")                                                               \
            for (int _j = 0; _j < 4; ++_j)                                                  \
                acc[_i][_j] = __builtin_amdgcn_mfma_f32_16x16x32_bf16(_af[_i], _bf[_j],     \
                                                                      acc[_i][_j], 0, 0, 0);\
        __builtin_amdgcn_s_setprio(0);                                                      \
    }

#define SYNC(VM)                                                                            \
    {                                                                                       \
        __builtin_amdgcn_sched_barrier(0);                                                  \
        asm volatile("s_waitcnt vmcnt(" #VM ")" ::: "memory");                              \
        __builtin_amdgcn_s_barrier();                                                       \
        __builtin_amdgcn_sched_barrier(0);                                                  \
    }

    // prologue: fill 3 ring slots, wait for tile 0 (leave 1,2 in flight)
    STAGE(0); STAGE(1); STAGE(2);
    SYNC(8);

    // main loop: stage t+3, compute t, wait so tile t+1 has landed
#pragma unroll 4
    for (int t = 0; t < K_TILES - 3; ++t) {
        STAGE(t + 3);
        KBODY(t);
        SYNC(8);
    }
    // epilogue peel: drain the ring (only place vmcnt goes below 8)
    KBODY(K_TILES - 3); SYNC(4);
    KBODY(K_TILES - 2); SYNC(0);
    KBODY(K_TILES - 1);

#undef STAGE
#undef KBODY
#undef SYNC

    // epilogue: D row=(lane>>4)*4+reg, col=lane&15 (m89-verified) ; add bias
#pragma unroll
    for (int j = 0; j < 4; ++j) {
        const int col = n0 + wnRow + j * 16 + lrow;
        const float bv = bias[col];
#pragma unroll
        for (int i = 0; i < 8; ++i) {
            const int rowb = m0 + wmRow + i * 16 + quad * 4;
#pragma unroll
            for (int r = 0; r < 4; ++r)
                out[(size_t)(rowb + r) * N_OUT + col] = acc[i][j][r] + bv;
        }
    }
}

// ---------------- fallback (round-1 fused kernel, used if ws too small) ----
#define LDS_STRIDE 40
__global__ __launch_bounds__(256)
void qlinear_fused_kernel(const float* __restrict__ x,
                          const int*   __restrict__ wq,
                          const float* __restrict__ scales,
                          const float* __restrict__ zeros,
                          const float* __restrict__ bias,
                          float*       __restrict__ out)
{
    __shared__ __bf16 As[128 * LDS_STRIDE];
    __shared__ __bf16 Bs[128 * LDS_STRIDE];
    const int tid  = threadIdx.x;
    const int m0   = blockIdx.x * 128;
    const int n0   = blockIdx.y * 128;
    const int wave = tid >> 6;
    const int lane = tid & 63;
    const int wm   = (wave & 1) * 64;
    const int wn   = (wave >> 1) * 64;
    const int lrow = lane & 15;
    const int quad = lane >> 4;
    const int srow = tid >> 3;
    const int scol = (tid & 7) * 4;

    f32x4 acc[4][4];
#pragma unroll
    for (int i = 0; i < 4; i++)
#pragma unroll
        for (int j = 0; j < 4; j++)
            acc[i][j] = (f32x4){0.f, 0.f, 0.f, 0.f};

    for (int k0 = 0; k0 < K_DIM; k0 += 32) {
        const int g = k0 >> 7;
#pragma unroll
        for (int rr = 0; rr < 4; rr++) {
            const int row = srow + rr * 32;
            const float4 v = *(const float4*)(x + (size_t)(m0 + row) * K_DIM + k0 + scol);
            bf16x4 b;
            b[0] = (__bf16)v.x; b[1] = (__bf16)v.y;
            b[2] = (__bf16)v.z; b[3] = (__bf16)v.w;
            *(bf16x4*)&As[row * LDS_STRIDE + scol] = b;
        }
#pragma unroll
        for (int rr = 0; rr < 4; rr++) {
            const int row = srow + rr * 32;
            const int4 q = *(const int4*)(wq + (size_t)(n0 + row) * K_DIM + k0 + scol);
            const float s = scales[(n0 + row) * NGROUPS + g];
            const float z = zeros [(n0 + row) * NGROUPS + g];
            bf16x4 b;
            b[0] = (__bf16)fmaf((float)q.x, s, z);
            b[1] = (__bf16)fmaf((float)q.y, s, z);
            b[2] = (__bf16)fmaf((float)q.z, s, z);
            b[3] = (__bf16)fmaf((float)q.w, s, z);
            *(bf16x4*)&Bs[row * LDS_STRIDE + scol] = b;
        }
        __syncthreads();
        bf16x8 af[4], bfr[4];
#pragma unroll
        for (int i = 0; i < 4; i++) {
            af[i]  = *(const bf16x8*)&As[(wm + i * 16 + lrow) * LDS_STRIDE + quad * 8];
            bfr[i] = *(const bf16x8*)&Bs[(wn + i * 16 + lrow) * LDS_STRIDE + quad * 8];
        }
#pragma unroll
        for (int i = 0; i < 4; i++)
#pragma unroll
            for (int j = 0; j < 4; j++)
                acc[i][j] = __builtin_amdgcn_mfma_f32_16x16x32_bf16(af[i], bfr[j], acc[i][j], 0, 0, 0);
        __syncthreads();
    }
#pragma unroll
    for (int j = 0; j < 4; j++) {
        const int col = n0 + wn + j * 16 + lrow;
        const float bv = bias[col];
#pragma unroll
        for (int i = 0; i < 4; i++) {
            const int rowb = m0 + wm + i * 16 + quad * 4;
#pragma unroll
            for (int r = 0; r < 4; r++)
                out[(size_t)(rowb + r) * N_OUT + col] = acc[i][j][r] + bv;
        }
    }
}

extern "C" void kernel_launch(void* const* d_in, const int* in_sizes, int n_in,
                              void* d_out, int out_size, void* d_ws, size_t ws_size,
                              hipStream_t stream) {
    const float* x      = (const float*)d_in[0];
    const int*   wq     = (const int*)  d_in[1];
    const float* scales = (const float*)d_in[2];
    const float* zeros  = (const float*)d_in[3];
    const float* bias   = (const float*)d_in[4];
    float*       out    = (float*)d_out;

    const size_t xb_bytes = (size_t)M_TOK * K_DIM * 2;   // 67.1 MB
    const size_t wb_bytes = (size_t)N_OUT * K_DIM * 2;   // 33.6 MB

    if (ws_size >= xb_bytes + wb_bytes) {
        __bf16* xb = (__bf16*)d_ws;
        __bf16* wb = (__bf16*)((char*)d_ws + xb_bytes);
        prep_kernel<<<XBLOCKS + WBLOCKS, 256, 0, stream>>>(x, xb, wq, scales, zeros, wb);
        dim3 grid((M_TOK / 256) * (N_OUT / 256));   // 512 wgs, 1D for XCD swizzle
        gemm_bt256_kernel<<<grid, 512, 0, stream>>>(xb, wb, bias, out);
    } else {
        dim3 grid(M_TOK / 128, N_OUT / 128);
        qlinear_fused_kernel<<<grid, 256, 0, stream>>>(x, wq, scales, zeros, bias, out);
    }
}